// Round 18
// baseline (389.874 us; speedup 1.0000x reference)
//
#include <hip/hip_runtime.h>
#include <hip/hip_bf16.h>
#include <cstdint>

#define B_ 2
#define T_ 2048
#define D_ 512
#define H_ 8
#define DK_ 64
#define TQ_ 4                 // rows per block
#define NTL_ (T_ / TQ_)       // 512 tiles per batch
#define M_ (B_ * T_)          // 4096

#define SSC_ 8192.0f          // score fixed-point scale (i16)
#define S2_  (SSC_ * SSC_)    // scaled Newton target

// ---------------- GEMM: C[M,N] = A[M,K] @ W[K,N] + bias[N] ----------------
__global__ __launch_bounds__(256) void gemm_bias_kernel(
    const float* __restrict__ A, const float* __restrict__ W,
    const float* __restrict__ bias, float* __restrict__ C,
    int M, int N, int K)
{
  __shared__ float As[32][68];  // transposed A tile: As[k][m]
  __shared__ float Bs[32][68];
  const int bm = blockIdx.y * 64;
  const int bn = blockIdx.x * 64;
  const int tid = threadIdx.x;
  const int tx = tid & 15, ty = tid >> 4;
  float acc[4][4] = {};
  for (int k0 = 0; k0 < K; k0 += 32) {
    {
      const int r = tid >> 2;           // 0..63
      const int c = (tid & 3) << 2;     // 0,4,8,12
      const float4 a0 = *reinterpret_cast<const float4*>(&A[(size_t)(bm + r) * K + k0 + c]);
      const float4 a1 = *reinterpret_cast<const float4*>(&A[(size_t)(bm + r) * K + k0 + 16 + c]);
      As[c + 0][r] = a0.x;  As[c + 1][r] = a0.y;  As[c + 2][r] = a0.z;  As[c + 3][r] = a0.w;
      As[c + 16][r] = a1.x; As[c + 17][r] = a1.y; As[c + 18][r] = a1.z; As[c + 19][r] = a1.w;
    }
    {
      const int r = tid >> 4;           // 0..15
      const int c = (tid & 15) << 2;    // 0..60
      *reinterpret_cast<float4*>(&Bs[r][c]) =
          *reinterpret_cast<const float4*>(&W[(size_t)(k0 + r) * N + bn + c]);
      *reinterpret_cast<float4*>(&Bs[r + 16][c]) =
          *reinterpret_cast<const float4*>(&W[(size_t)(k0 + 16 + r) * N + bn + c]);
    }
    __syncthreads();
#pragma unroll
    for (int kk = 0; kk < 32; ++kk) {
      const float4 av = *reinterpret_cast<const float4*>(&As[kk][ty * 4]);
      const float4 bv = *reinterpret_cast<const float4*>(&Bs[kk][tx * 4]);
      acc[0][0] = fmaf(av.x, bv.x, acc[0][0]); acc[0][1] = fmaf(av.x, bv.y, acc[0][1]);
      acc[0][2] = fmaf(av.x, bv.z, acc[0][2]); acc[0][3] = fmaf(av.x, bv.w, acc[0][3]);
      acc[1][0] = fmaf(av.y, bv.x, acc[1][0]); acc[1][1] = fmaf(av.y, bv.y, acc[1][1]);
      acc[1][2] = fmaf(av.y, bv.z, acc[1][2]); acc[1][3] = fmaf(av.y, bv.w, acc[1][3]);
      acc[2][0] = fmaf(av.z, bv.x, acc[2][0]); acc[2][1] = fmaf(av.z, bv.y, acc[2][1]);
      acc[2][2] = fmaf(av.z, bv.z, acc[2][2]); acc[2][3] = fmaf(av.z, bv.w, acc[2][3]);
      acc[3][0] = fmaf(av.w, bv.x, acc[3][0]); acc[3][1] = fmaf(av.w, bv.y, acc[3][1]);
      acc[3][2] = fmaf(av.w, bv.z, acc[3][2]); acc[3][3] = fmaf(av.w, bv.w, acc[3][3]);
    }
    __syncthreads();
  }
#pragma unroll
  for (int i = 0; i < 4; ++i) {
    const int row = bm + ty * 4 + i;
#pragma unroll
    for (int j = 0; j < 4; ++j) {
      const int col = bn + tx * 4 + j;
      C[(size_t)row * N + col] = acc[i][j] + bias[col];
    }
  }
}

// Same GEMM but writes C TRANSPOSED: Ct[N][M].
__global__ __launch_bounds__(256) void gemm_bias_kernelT(
    const float* __restrict__ A, const float* __restrict__ W,
    const float* __restrict__ bias, float* __restrict__ Ct,
    int M, int N, int K)
{
  __shared__ float As[32][68];
  __shared__ float Bs[32][68];
  const int bm = blockIdx.y * 64;
  const int bn = blockIdx.x * 64;
  const int tid = threadIdx.x;
  const int tx = tid & 15, ty = tid >> 4;
  float acc[4][4] = {};
  for (int k0 = 0; k0 < K; k0 += 32) {
    {
      const int r = tid >> 2;
      const int c = (tid & 3) << 2;
      const float4 a0 = *reinterpret_cast<const float4*>(&A[(size_t)(bm + r) * K + k0 + c]);
      const float4 a1 = *reinterpret_cast<const float4*>(&A[(size_t)(bm + r) * K + k0 + 16 + c]);
      As[c + 0][r] = a0.x;  As[c + 1][r] = a0.y;  As[c + 2][r] = a0.z;  As[c + 3][r] = a0.w;
      As[c + 16][r] = a1.x; As[c + 17][r] = a1.y; As[c + 18][r] = a1.z; As[c + 19][r] = a1.w;
    }
    {
      const int r = tid >> 4;
      const int c = (tid & 15) << 2;
      *reinterpret_cast<float4*>(&Bs[r][c]) =
          *reinterpret_cast<const float4*>(&W[(size_t)(k0 + r) * N + bn + c]);
      *reinterpret_cast<float4*>(&Bs[r + 16][c]) =
          *reinterpret_cast<const float4*>(&W[(size_t)(k0 + 16 + r) * N + bn + c]);
    }
    __syncthreads();
#pragma unroll
    for (int kk = 0; kk < 32; ++kk) {
      const float4 av = *reinterpret_cast<const float4*>(&As[kk][ty * 4]);
      const float4 bv = *reinterpret_cast<const float4*>(&Bs[kk][tx * 4]);
      acc[0][0] = fmaf(av.x, bv.x, acc[0][0]); acc[0][1] = fmaf(av.x, bv.y, acc[0][1]);
      acc[0][2] = fmaf(av.x, bv.z, acc[0][2]); acc[0][3] = fmaf(av.x, bv.w, acc[0][3]);
      acc[1][0] = fmaf(av.y, bv.x, acc[1][0]); acc[1][1] = fmaf(av.y, bv.y, acc[1][1]);
      acc[1][2] = fmaf(av.y, bv.z, acc[1][2]); acc[1][3] = fmaf(av.y, bv.w, acc[1][3]);
      acc[2][0] = fmaf(av.z, bv.x, acc[2][0]); acc[2][1] = fmaf(av.z, bv.y, acc[2][1]);
      acc[2][2] = fmaf(av.z, bv.z, acc[2][2]); acc[2][3] = fmaf(av.z, bv.w, acc[2][3]);
      acc[3][0] = fmaf(av.w, bv.x, acc[3][0]); acc[3][1] = fmaf(av.w, bv.y, acc[3][1]);
      acc[3][2] = fmaf(av.w, bv.z, acc[3][2]); acc[3][3] = fmaf(av.w, bv.w, acc[3][3]);
    }
    __syncthreads();
  }
#pragma unroll
  for (int j = 0; j < 4; ++j) {
    const int col = bn + tx * 4 + j;
    const float bb = bias[col];
    const float4 v = make_float4(acc[0][j] + bb, acc[1][j] + bb, acc[2][j] + bb, acc[3][j] + bb);
    *reinterpret_cast<float4*>(&Ct[(size_t)col * M + bm + ty * 4]) = v;
  }
}

// ---------------- V_combined = mean over heads of V ----------------
__global__ __launch_bounds__(256) void vcombine_kernel(const float* __restrict__ V,
                                                       float* __restrict__ Vc)
{
  const int idx = blockIdx.x * 256 + threadIdx.x;
  if (idx >= M_ * DK_) return;
  const int row = idx >> 6, d = idx & 63;
  float s = 0.f;
#pragma unroll
  for (int h = 0; h < H_; ++h) s += V[(size_t)row * D_ + h * DK_ + d];
  Vc[idx] = s * 0.125f;
}

// ---------------- zero-fill wavg ----------------
__global__ __launch_bounds__(256) void zero_kernel(float4* __restrict__ p, int n4)
{
  const int stride = gridDim.x * 256;
  const float4 z = make_float4(0.f, 0.f, 0.f, 0.f);
  for (int i = blockIdx.x * 256 + threadIdx.x; i < n4; i += stride) p[i] = z;
}

// ---------------- per-(head, 4-row-tile) scores + exact entmax, atomic wavg ----------------
// r15 structure exactly: epilogue is the sparse atomic scatter ONLY (the fused
// ballot/ffs PV walk of r16/r17 cost +90us — reverted).
__global__ __launch_bounds__(256, 6)
void attn_kernel(
    const float* __restrict__ Qg, const float* __restrict__ Kt,
    float* __restrict__ wavg)
{
  __shared__ short ssc[TQ_][T_];            // 16 KB

  const int tid = threadIdx.x;
  const int bid = blockIdx.x;
  const int h = bid >> 10;                  // 0..7
  const int b = (bid >> 9) & 1;
  const int tile = (NTL_ - 1) - (bid & 511);  // heavy tiles first
  const int t0 = tile * TQ_;
  const int nS = t0 + TQ_;
  const int wave = __builtin_amdgcn_readfirstlane(tid >> 6);  // 0..3 (SGPR)
  const int lane = tid & 63;

  // ---- scores -> i16 * 8192 ----
  {
    const float* Qp = &Qg[(size_t)(b * T_ + t0) * D_ + h * DK_];  // block-uniform
#pragma unroll 1
    for (int c = 0; c < T_; c += 1024) {
      if (c < nS) {                              // SCALAR guard
        const int s0 = min(tid * 4 + c, nS - 4); // clamp: duplicates write same values
        const float* Ktp = &Kt[(size_t)(h * DK_) * M_ + b * T_ + s0];
        float4 a[TQ_];
#pragma unroll
        for (int r = 0; r < TQ_; ++r) a[r] = make_float4(0.f, 0.f, 0.f, 0.f);
#pragma unroll 2
        for (int d4 = 0; d4 < 16; ++d4) {
          const float4 k0 = *reinterpret_cast<const float4*>(Ktp + (size_t)(d4 * 4 + 0) * M_);
          const float4 k1 = *reinterpret_cast<const float4*>(Ktp + (size_t)(d4 * 4 + 1) * M_);
          const float4 k2 = *reinterpret_cast<const float4*>(Ktp + (size_t)(d4 * 4 + 2) * M_);
          const float4 k3 = *reinterpret_cast<const float4*>(Ktp + (size_t)(d4 * 4 + 3) * M_);
#pragma unroll
          for (int r = 0; r < TQ_; ++r) {
            const float q0 = Qp[r * D_ + d4 * 4 + 0];  // scalar loads (uniform)
            const float q1 = Qp[r * D_ + d4 * 4 + 1];
            const float q2 = Qp[r * D_ + d4 * 4 + 2];
            const float q3 = Qp[r * D_ + d4 * 4 + 3];
            a[r].x = fmaf(q0, k0.x, a[r].x); a[r].y = fmaf(q0, k0.y, a[r].y);
            a[r].z = fmaf(q0, k0.z, a[r].z); a[r].w = fmaf(q0, k0.w, a[r].w);
            a[r].x = fmaf(q1, k1.x, a[r].x); a[r].y = fmaf(q1, k1.y, a[r].y);
            a[r].z = fmaf(q1, k1.z, a[r].z); a[r].w = fmaf(q1, k1.w, a[r].w);
            a[r].x = fmaf(q2, k2.x, a[r].x); a[r].y = fmaf(q2, k2.y, a[r].y);
            a[r].z = fmaf(q2, k2.z, a[r].z); a[r].w = fmaf(q2, k2.w, a[r].w);
            a[r].x = fmaf(q3, k3.x, a[r].x); a[r].y = fmaf(q3, k3.y, a[r].y);
            a[r].z = fmaf(q3, k3.z, a[r].z); a[r].w = fmaf(q3, k3.w, a[r].w);
          }
        }
        // z_scaled = dot * 0.0625 * 8192 = dot * 512
#pragma unroll
        for (int r = 0; r < TQ_; ++r) {
          const int i0 = __float2int_rn(fminf(fmaxf(a[r].x * 512.f, -32000.f), 32000.f));
          const int i1 = __float2int_rn(fminf(fmaxf(a[r].y * 512.f, -32000.f), 32000.f));
          const int i2 = __float2int_rn(fminf(fmaxf(a[r].z * 512.f, -32000.f), 32000.f));
          const int i3 = __float2int_rn(fminf(fmaxf(a[r].w * 512.f, -32000.f), 32000.f));
          short4 st; st.x = (short)i0; st.y = (short)i1; st.z = (short)i2; st.w = (short)i3;
          *reinterpret_cast<short4*>(&ssc[r][s0]) = st;
        }
      }
    }
  }
  __syncthreads();

  // ---- entmax on row t0+wave (exact, register-resident) ----
  const int t = t0 + wave;
  const int n = t + 1;                      // SGPR support size
  float srow[32];                           // s = j*512 + lane*8 + q

#pragma unroll
  for (int j = 0; j < 4; ++j) {
    if (j * 512 < n) {                      // scalar guard
      const uint4 pk = *reinterpret_cast<const uint4*>(&ssc[wave][j * 512 + lane * 8]);
      const unsigned pw[4] = {pk.x, pk.y, pk.z, pk.w};
#pragma unroll
      for (int q = 0; q < 4; ++q) {
        const int s_lo = j * 512 + lane * 8 + q * 2;
        const float lo = (float)((int)(short)(pw[q] & 0xffffu));
        const float hi = (float)((int)pw[q] >> 16);
        srow[j * 8 + q * 2 + 0] = (s_lo + 0 < n) ? lo : -1e30f;
        srow[j * 8 + q * 2 + 1] = (s_lo + 1 < n) ? hi : -1e30f;
      }
    } else {
#pragma unroll
      for (int q = 0; q < 8; ++q) srow[j * 8 + q] = -1e30f;
    }
  }
  asm volatile("" ::: "memory");            // keep srow in registers

  float mx = -1e30f;
#pragma unroll
  for (int i = 0; i < 32; ++i) mx = fmaxf(mx, srow[i]);
#pragma unroll
  for (int m = 32; m >= 1; m >>= 1) mx = fmaxf(mx, __shfl_xor(mx, m, 64));

  float tau = mx - SSC_;                    // f(tau0) >= 0
#pragma unroll 1
  for (int it = 0; it < 12; ++it) {
    float s1 = 0.f, s2 = 0.f, cn = 0.f;
#pragma unroll
    for (int j = 0; j < 4; ++j) {
      if (j * 512 < n) {
#pragma unroll
        for (int q = 0; q < 8; ++q) {
          const float u = fmaxf(srow[j * 8 + q] - tau, 0.f);
          s1 += u;
          s2 = fmaf(u, u, s2);
          cn += (u > 0.f) ? 1.f : 0.f;
        }
      }
    }
#pragma unroll
    for (int m = 32; m >= 1; m >>= 1) {
      s1 += __shfl_xor(s1, m, 64);
      s2 += __shfl_xor(s2, m, 64);
    }
    if (fabsf(s2 - S2_) < 672.f) break;     // 1e-5 relative
    if (it < 3) {
#pragma unroll
      for (int m = 32; m >= 1; m >>= 1) cn += __shfl_xor(cn, m, 64);
      const float kf = fmaxf(cn, 1.f);
      const float mu = tau + s1 / kf;
      const float ss = s2 - s1 * s1 / kf;
      tau = mu - sqrtf(fmaxf((S2_ - ss) / kf, 0.f));  // exact tau on current support
    } else {
      tau += (s2 - S2_) / fmaxf(2.f * s1, 1e-6f);     // Newton
    }
  }
  tau = fminf(tau, mx - 1.f);

  // ---- scatter nonzero weights: wavg += (u/8192)^2 * 0.125 ----
  const float wconv = 0.125f / (SSC_ * SSC_);
  float* const wrow = &wavg[(size_t)(b * T_ + t) * T_];
#pragma unroll
  for (int j = 0; j < 4; ++j) {
    if (j * 512 < n) {
#pragma unroll
      for (int q = 0; q < 8; ++q) {
        const float u = fmaxf(srow[j * 8 + q] - tau, 0.f);
        if (__any(u > 0.f)) {
          if (u > 0.f) {
            const int s = j * 512 + lane * 8 + q;
            atomicAdd(&wrow[s], u * u * wconv);
          }
        }
      }
    }
  }
}

// ---------------- PV: one block per row; skip all-zero quads; 2-deep prefetch ----------------
// The next quad's float4 load is issued BEFORE the current quad's nz-test, so the
// ~300-cycle load latency overlaps the dependent test/FMA of the previous quad.
__global__ __launch_bounds__(256) void pv_kernel(
    const float* __restrict__ wavg, const float* __restrict__ Vc,
    float* __restrict__ AO)
{
  __shared__ float part[4][DK_];
  const int row = blockIdx.x;               // 0..M_-1
  const int b = row >> 11;
  const int t = row & (T_ - 1);
  const int wave = __builtin_amdgcn_readfirstlane(threadIdx.x >> 6);
  const int lane = threadIdx.x & 63;
  const int n = t + 1;
  const float* wr = &wavg[(size_t)row * T_];
  const float* vb = &Vc[(size_t)(b * T_) * DK_ + lane];
  float acc = 0.f;
  int s0 = wave * 4;
  float4 w4 = make_float4(0.f, 0.f, 0.f, 0.f);
  if (s0 < n) w4 = *reinterpret_cast<const float4*>(&wr[s0]);
#pragma unroll 1
  while (s0 < n) {
    const int s1 = s0 + 16;
    float4 w4n = make_float4(0.f, 0.f, 0.f, 0.f);
    if (s1 < n) w4n = *reinterpret_cast<const float4*>(&wr[s1]);  // prefetch next
    const unsigned nz = __float_as_uint(w4.x) | __float_as_uint(w4.y) |
                        __float_as_uint(w4.z) | __float_as_uint(w4.w);
    if (__builtin_amdgcn_readfirstlane(nz) != 0u) {   // scalar branch
      acc = fmaf(w4.x, vb[(size_t)(s0 + 0) * DK_], acc);
      acc = fmaf(w4.y, vb[(size_t)(s0 + 1) * DK_], acc);
      acc = fmaf(w4.z, vb[(size_t)(s0 + 2) * DK_], acc);
      acc = fmaf(w4.w, vb[(size_t)(s0 + 3) * DK_], acc);
    }
    w4 = w4n;
    s0 = s1;
  }
  part[wave][lane] = acc;
  __syncthreads();
  if (wave == 0) {
    AO[(size_t)row * DK_ + lane] =
        part[0][lane] + part[1][lane] + part[2][lane] + part[3][lane];
  }
}

extern "C" void kernel_launch(void* const* d_in, const int* in_sizes, int n_in,
                              void* d_out, int out_size, void* d_ws, size_t ws_size,
                              hipStream_t stream)
{
  const float* x  = (const float*)d_in[0];
  const float* Wq = (const float*)d_in[1];
  const float* bq = (const float*)d_in[2];
  const float* Wk = (const float*)d_in[3];
  const float* bk = (const float*)d_in[4];
  const float* Wv = (const float*)d_in[5];
  const float* bv = (const float*)d_in[6];
  const float* Wo = (const float*)d_in[7];
  const float* bo = (const float*)d_in[8];
  float* out = (float*)d_out;
  float* ws  = (float*)d_ws;

  float* Q  = ws;                        // [M,512]
  float* Kt = Q + (size_t)M_ * D_;       // [512,M]
  float* V  = Kt + (size_t)D_ * M_;      // [M,512]
  float* Vc = V + (size_t)M_ * D_;       // [M,64]
  float* AO = Vc + (size_t)M_ * DK_;     // [M,64]

  float* out1 = out;                    // [B,T,D]
  float* wavg = out + (size_t)M_ * D_;  // [B,T,T]

  const dim3 gp(D_ / 64, M_ / 64);  // (8, 64)
  gemm_bias_kernel <<<gp, 256, 0, stream>>>(x, Wq, bq, Q,  M_, D_, D_);
  gemm_bias_kernelT<<<gp, 256, 0, stream>>>(x, Wk, bk, Kt, M_, D_, D_);
  gemm_bias_kernel <<<gp, 256, 0, stream>>>(x, Wv, bv, V,  M_, D_, D_);
  vcombine_kernel<<<(M_ * DK_ + 255) / 256, 256, 0, stream>>>(V, Vc);

  zero_kernel<<<2048, 256, 0, stream>>>(reinterpret_cast<float4*>(wavg),
                                        (int)((size_t)B_ * T_ * T_ / 4));

  attn_kernel<<<H_ * B_ * NTL_, 256, 0, stream>>>(Q, Kt, wavg);
  pv_kernel<<<M_, 256, 0, stream>>>(wavg, Vc, AO);
  gemm_bias_kernel<<<gp, 256, 0, stream>>>(AO, Wo, bo, out1, M_, D_, DK_);
}